// Round 5
// baseline (1338.267 us; speedup 1.0000x reference)
//
#include <hip/hip_runtime.h>
#include <hip/hip_bf16.h>
#include <math.h>

#define NNODES 50000
#define NEDGES 640000
#define NGRAPH 256
#define CIN 32
#define HD 128
#define NLAYER 5
#define LHID 64
#define COUT 10
#define EPS_GEN 1e-7f
#define INVN (1.f / (float)NNODES)
#define SCAN_BLOCKS 196

// ---------------- CSR build ----------------
__global__ void hist_kernel(const int* __restrict__ dst, int* __restrict__ deg, int e) {
    int i = blockIdx.x * blockDim.x + threadIdx.x;
    if (i < e) atomicAdd(&deg[dst[i]], 1);
}

__global__ void blocksum_kernel(const int* __restrict__ deg, int* __restrict__ bsum) {
    int i = blockIdx.x * 256 + threadIdx.x;
    int v = (i < NNODES) ? deg[i] : 0;
#pragma unroll
    for (int d = 32; d; d >>= 1) v += __shfl_down(v, d);
    __shared__ int ws4[4];
    if ((threadIdx.x & 63) == 0) ws4[threadIdx.x >> 6] = v;
    __syncthreads();
    if (threadIdx.x == 0) bsum[blockIdx.x] = ws4[0] + ws4[1] + ws4[2] + ws4[3];
}

__global__ void scanpartials_kernel(const int* __restrict__ bsum, int* __restrict__ bpre) {
    __shared__ int t[256];
    int i = threadIdx.x;
    t[i] = (i < SCAN_BLOCKS) ? bsum[i] : 0;
    __syncthreads();
    for (int d = 1; d < 256; d <<= 1) {
        int v = (i >= d) ? t[i - d] : 0;
        __syncthreads();
        t[i] += v;
        __syncthreads();
    }
    bpre[i] = (i == 0) ? 0 : t[i - 1];
}

__global__ void writeoff_kernel(const int* __restrict__ deg, const int* __restrict__ bpre,
                                int* __restrict__ off, int* __restrict__ cursor) {
    __shared__ int t[256];
    int tid = threadIdx.x;
    int i = blockIdx.x * 256 + tid;
    int v = (i < NNODES) ? deg[i] : 0;
    t[tid] = v;
    __syncthreads();
    for (int d = 1; d < 256; d <<= 1) {
        int u = (tid >= d) ? t[tid - d] : 0;
        __syncthreads();
        t[tid] += u;
        __syncthreads();
    }
    int excl = bpre[blockIdx.x] + t[tid] - v;
    if (i < NNODES) { off[i] = excl; cursor[i] = excl; }
    if (i == NNODES - 1) off[NNODES] = excl + v;
}

__global__ void scatter_kernel(const int* __restrict__ src, const int* __restrict__ dst,
                               const int* __restrict__ eattr, int* __restrict__ cursor,
                               int* __restrict__ pedge, int e) {
    int i = blockIdx.x * blockDim.x + threadIdx.x;
    if (i < e) {
        int slot = atomicAdd(&cursor[dst[i]], 1);
        pedge[slot] = src[i] | (eattr[i] << 27);
    }
}

// ---------------- input FC (LDS-staged weights, 8 nodes/block) ----------------
__global__ __launch_bounds__(256) void fc_kernel(
    const float* __restrict__ x, const float* __restrict__ ncc,
    const float* __restrict__ w, const float* __restrict__ b,
    float* __restrict__ h) {
    __shared__ float ws[HD][41];
    __shared__ float bs[HD];
    int tid = threadIdx.x;
    for (int i = tid; i < HD * 40; i += 256) ws[i / 40][i % 40] = w[i];
    if (tid < HD) bs[tid] = b[tid];
    __syncthreads();
    int c = tid & 127;
    int hi = tid >> 7;
#pragma unroll
    for (int nn = 0; nn < 4; ++nn) {
        int node = blockIdx.x * 8 + nn * 2 + hi;
        const float4* xr = reinterpret_cast<const float4*>(x + (size_t)node * CIN);
        const float4* nr = reinterpret_cast<const float4*>(ncc + (size_t)node * 8);
        float acc = bs[c];
#pragma unroll
        for (int k4 = 0; k4 < 8; ++k4) {
            float4 xv = xr[k4];
            acc += xv.x * ws[c][k4 * 4 + 0];
            acc += xv.y * ws[c][k4 * 4 + 1];
            acc += xv.z * ws[c][k4 * 4 + 2];
            acc += xv.w * ws[c][k4 * 4 + 3];
        }
#pragma unroll
        for (int k4 = 0; k4 < 2; ++k4) {
            float4 nv = nr[k4];
            acc += nv.x * ws[c][32 + k4 * 4 + 0];
            acc += nv.y * ws[c][32 + k4 * 4 + 1];
            acc += nv.z * ws[c][32 + k4 * 4 + 2];
            acc += nv.w * ws[c][32 + k4 * 4 + 3];
        }
        h[(size_t)node * HD + c] = acc;
    }
}

// ---------------- softmax aggregation (edge-word prefetch) ----------------
template <bool BN>
__global__ __launch_bounds__(256) void agg_kernel(
    const float* __restrict__ h, const int* __restrict__ off,
    const int* __restrict__ pedge, const float* __restrict__ edge_emb,
    const float* __restrict__ sums, const float* __restrict__ sqs,
    const float* __restrict__ g, const float* __restrict__ bb,
    float* __restrict__ x0) {
    __shared__ float ee[4 * HD];
    __shared__ float scs[HD], shs[HD];
    int tid = threadIdx.x;
    ee[tid] = edge_emb[tid];
    ee[tid + 256] = edge_emb[tid + 256];
    if (BN && tid < HD) {
        float mu = sums[tid] * INVN;
        float var = fmaxf(sqs[tid] * INVN - mu * mu, 0.f);
        float is = rsqrtf(var + 1e-5f);
        float sc = g[tid] * is;
        scs[tid] = sc;
        shs[tid] = bb[tid] - mu * sc;
    }
    __syncthreads();

    int node = blockIdx.x * 4 + (tid >> 6);
    int lane = tid & 63;
    int half = lane >> 5;
    int c4 = (lane & 31) * 4;

    int b = off[node], e = off[node + 1];
    float4 sc4 = make_float4(1.f, 1.f, 1.f, 1.f);
    float4 sh4 = make_float4(0.f, 0.f, 0.f, 0.f);
    if (BN) {
        sc4 = *reinterpret_cast<const float4*>(&scs[c4]);
        sh4 = *reinterpret_cast<const float4*>(&shs[c4]);
    }
    float4 S = make_float4(0.f, 0.f, 0.f, 0.f);
    float4 T = make_float4(0.f, 0.f, 0.f, 0.f);
    int j = b + half;
    unsigned pnext = (j < e) ? (unsigned)pedge[j] : 0u;
    for (; j < e; j += 2) {
        unsigned p = pnext;
        if (j + 2 < e) pnext = (unsigned)pedge[j + 2];
        int s = p & 0x07FFFFFFu;
        int a = p >> 27;
        float4 v = *reinterpret_cast<const float4*>(&h[(size_t)s * HD + c4]);
        float4 ev = *reinterpret_cast<const float4*>(&ee[a * HD + c4]);
        if (BN) {
            v.x = fmaxf(fmaf(v.x, sc4.x, sh4.x), 0.f);
            v.y = fmaxf(fmaf(v.y, sc4.y, sh4.y), 0.f);
            v.z = fmaxf(fmaf(v.z, sc4.z, sh4.z), 0.f);
            v.w = fmaxf(fmaf(v.w, sc4.w, sh4.w), 0.f);
        }
        float m0 = fmaxf(v.x + ev.x, 0.f) + EPS_GEN;
        float m1 = fmaxf(v.y + ev.y, 0.f) + EPS_GEN;
        float m2 = fmaxf(v.z + ev.z, 0.f) + EPS_GEN;
        float m3 = fmaxf(v.w + ev.w, 0.f) + EPS_GEN;
        float e0 = __expf(m0), e1 = __expf(m1), e2 = __expf(m2), e3 = __expf(m3);
        S.x += e0; S.y += e1; S.z += e2; S.w += e3;
        T.x = fmaf(e0, m0, T.x); T.y = fmaf(e1, m1, T.y);
        T.z = fmaf(e2, m2, T.z); T.w = fmaf(e3, m3, T.w);
    }
    S.x += __shfl(S.x, lane ^ 32); S.y += __shfl(S.y, lane ^ 32);
    S.z += __shfl(S.z, lane ^ 32); S.w += __shfl(S.w, lane ^ 32);
    T.x += __shfl(T.x, lane ^ 32); T.y += __shfl(T.y, lane ^ 32);
    T.z += __shfl(T.z, lane ^ 32); T.w += __shfl(T.w, lane ^ 32);
    if (half == 0) {
        float4 r = *reinterpret_cast<const float4*>(&h[(size_t)node * HD + c4]);
        if (BN) {
            r.x = fmaxf(fmaf(r.x, sc4.x, sh4.x), 0.f);
            r.y = fmaxf(fmaf(r.y, sc4.y, sh4.y), 0.f);
            r.z = fmaxf(fmaf(r.z, sc4.z, sh4.z), 0.f);
            r.w = fmaxf(fmaf(r.w, sc4.w, sh4.w), 0.f);
        }
        if (e > b) {
            r.x += T.x / S.x; r.y += T.y / S.y;
            r.z += T.z / S.z; r.w += T.w / S.w;
        }
        *reinterpret_cast<float4*>(&x0[(size_t)node * HD + c4]) = r;
    }
}

// ---------------- fp32 GEMM 128x128 tile, BK=16, 512 thr, reg-prefetch pipeline ----------------
// C = op(A) @ W^T + bias; op = relu(a*scale+shift) (TRANS, scale/shift from raw sums).
// Fused column sum/sumsq stats of C. Microtile 4 rows x (4+4) cols per thread.
template <bool TRANS>
__global__ __launch_bounds__(512) void gemm_kernel(
    const float* __restrict__ A, const float* __restrict__ W,
    const float* __restrict__ bias,
    const float* __restrict__ sums_in, const float* __restrict__ sqs_in,
    const float* __restrict__ g_in, const float* __restrict__ b_in,
    float* __restrict__ C, float* __restrict__ sums, float* __restrict__ sqs,
    int M, int Nc, int K) {
    __shared__ float As[16][132];
    __shared__ float Bs[16][132];
    __shared__ float scol[128];
    __shared__ float sqcol[128];
    __shared__ float sL[256], shL[256];
    int tid = threadIdx.x;
    if (tid < 128) { scol[tid] = 0.f; sqcol[tid] = 0.f; }
    if (TRANS && tid < K) {
        float mu = sums_in[tid] * INVN;
        float var = fmaxf(sqs_in[tid] * INVN - mu * mu, 0.f);
        float is = rsqrtf(var + 1e-5f);
        float sc = g_in[tid] * is;
        sL[tid] = sc;
        shL[tid] = b_in[tid] - mu * sc;
    }
    __syncthreads();

    int m0 = blockIdx.x * 128;
    int n0 = blockIdx.y * 128;
    int ldr = tid >> 2;            // 0..127
    int ldk = (tid & 3) * 4;       // 0,4,8,12
    int rowg = tid >> 4;           // 0..31 -> rows rowg*4..+3
    int colg = tid & 15;           // 0..15 -> cols colg*4..+3 and 64+colg*4..+3

    float acc[4][8];
#pragma unroll
    for (int i = 0; i < 4; ++i)
#pragma unroll
        for (int j = 0; j < 8; ++j) acc[i][j] = 0.f;

    int am = m0 + ldr;
    bool mok = am < M;
    const float* aptr = &A[(size_t)(mok ? am : 0) * K + ldk];
    const float* wptr = &W[(size_t)(n0 + ldr) * K + ldk];

    float4 ar = mok ? *reinterpret_cast<const float4*>(aptr)
                    : make_float4(0.f, 0.f, 0.f, 0.f);
    float4 wr = *reinterpret_cast<const float4*>(wptr);

    int niter = K >> 4;
    for (int it = 0; it < niter; ++it) {
        float4 a = ar, wv = wr;
        if (TRANS) {
            int kg = it * 16 + ldk;
            a.x = fmaxf(fmaf(a.x, sL[kg + 0], shL[kg + 0]), 0.f);
            a.y = fmaxf(fmaf(a.y, sL[kg + 1], shL[kg + 1]), 0.f);
            a.z = fmaxf(fmaf(a.z, sL[kg + 2], shL[kg + 2]), 0.f);
            a.w = fmaxf(fmaf(a.w, sL[kg + 3], shL[kg + 3]), 0.f);
        }
        As[ldk + 0][ldr] = a.x; As[ldk + 1][ldr] = a.y;
        As[ldk + 2][ldr] = a.z; As[ldk + 3][ldr] = a.w;
        Bs[ldk + 0][ldr] = wv.x; Bs[ldk + 1][ldr] = wv.y;
        Bs[ldk + 2][ldr] = wv.z; Bs[ldk + 3][ldr] = wv.w;
        __syncthreads();
        if (it + 1 < niter) {
            // prefetch next tile; latency hidden under the 16-step FMA loop
            int koff = (it + 1) * 16;
            ar = mok ? *reinterpret_cast<const float4*>(aptr + koff)
                     : make_float4(0.f, 0.f, 0.f, 0.f);
            wr = *reinterpret_cast<const float4*>(wptr + koff);
        }
#pragma unroll
        for (int kk = 0; kk < 16; ++kk) {
            float4 av = *reinterpret_cast<const float4*>(&As[kk][rowg * 4]);
            float4 b0 = *reinterpret_cast<const float4*>(&Bs[kk][colg * 4]);
            float4 b1 = *reinterpret_cast<const float4*>(&Bs[kk][64 + colg * 4]);
            float avv[4] = {av.x, av.y, av.z, av.w};
            float bvv[8] = {b0.x, b0.y, b0.z, b0.w, b1.x, b1.y, b1.z, b1.w};
#pragma unroll
            for (int i = 0; i < 4; ++i)
#pragma unroll
                for (int j = 0; j < 8; ++j) acc[i][j] = fmaf(avv[i], bvv[j], acc[i][j]);
        }
        __syncthreads();
    }

    float bj[8];
#pragma unroll
    for (int j = 0; j < 4; ++j) {
        bj[j] = bias[n0 + colg * 4 + j];
        bj[j + 4] = bias[n0 + 64 + colg * 4 + j];
    }

#pragma unroll
    for (int i = 0; i < 4; ++i) {
        int m = m0 + rowg * 4 + i;
        if (m < M) {
            float* cp = &C[(size_t)m * Nc + n0 + colg * 4];
            *reinterpret_cast<float4*>(cp) = make_float4(
                acc[i][0] + bj[0], acc[i][1] + bj[1],
                acc[i][2] + bj[2], acc[i][3] + bj[3]);
            *reinterpret_cast<float4*>(cp + 64) = make_float4(
                acc[i][4] + bj[4], acc[i][5] + bj[5],
                acc[i][6] + bj[6], acc[i][7] + bj[7]);
        }
    }
#pragma unroll
    for (int j = 0; j < 8; ++j) {
        float cs = 0.f, cq = 0.f;
#pragma unroll
        for (int i = 0; i < 4; ++i) {
            int m = m0 + rowg * 4 + i;
            if (m < M) {
                float v = acc[i][j] + bj[j];
                cs += v; cq += v * v;
            }
        }
        int col = (j >> 2) * 64 + colg * 4 + (j & 3);
        atomicAdd(&scol[col], cs);
        atomicAdd(&sqcol[col], cq);
    }
    __syncthreads();
    if (tid < 128) {
        atomicAdd(&sums[n0 + tid], scol[tid]);
        atomicAdd(&sqs[n0 + tid], sqcol[tid]);
    }
}

// ---------------- segmented pool + folded final BN+ReLU ----------------
__global__ void pool_kernel(const float* __restrict__ h, const int* __restrict__ batch,
                            const float* __restrict__ sums, const float* __restrict__ sqs,
                            const float* __restrict__ g, const float* __restrict__ bb,
                            float* __restrict__ p) {
    __shared__ int range[2];
    __shared__ float acc2[256];
    int gid = blockIdx.x;
    int tid = threadIdx.x;
    if (tid < 2) {
        int target = gid + tid;
        int lo = 0, hi = NNODES;
        while (lo < hi) {
            int mid = (lo + hi) >> 1;
            if (batch[mid] < target) lo = mid + 1; else hi = mid;
        }
        range[tid] = lo;
    }
    __syncthreads();
    int s0 = range[0], s1 = range[1];
    int c = tid & 127;
    int half = tid >> 7;
    float mu = sums[c] * INVN;
    float var = fmaxf(sqs[c] * INVN - mu * mu, 0.f);
    float is = rsqrtf(var + 1e-5f);
    float sc = g[c] * is;
    float sh = bb[c] - mu * sc;
    float a = 0.f;
    for (int r = s0 + half; r < s1; r += 2)
        a += fmaxf(fmaf(h[(size_t)r * HD + c], sc, sh), 0.f);
    acc2[tid] = a;
    __syncthreads();
    if (half == 0) p[gid * HD + c] = acc2[c] + acc2[c + 128];
}

// ---------------- LSTM (1 step) + final linear ----------------
__global__ void lstm_kernel(const float* __restrict__ p, const float* __restrict__ wih,
                            const float* __restrict__ bih, const float* __restrict__ bhh,
                            const float* __restrict__ lin_w, const float* __restrict__ lin_b,
                            float* __restrict__ out) {
    __shared__ float pr[HD];
    __shared__ float gates[4 * LHID];
    __shared__ float hh[LHID];
    int g = blockIdx.x;
    int t = threadIdx.x;
    if (t < HD) pr[t] = p[g * HD + t];
    __syncthreads();
    {
        float acc = bih[t] + bhh[t];
        const float* wr = wih + t * HD;
        for (int k = 0; k < HD; ++k) acc += pr[k] * wr[k];
        gates[t] = acc;
    }
    __syncthreads();
    if (t < LHID) {
        float ig = gates[t];
        float gg = gates[2 * LHID + t];
        float og = gates[3 * LHID + t];
        float c = (1.f / (1.f + __expf(-ig))) * tanhf(gg);
        hh[t] = (1.f / (1.f + __expf(-og))) * tanhf(c);
    }
    __syncthreads();
    if (t < COUT) {
        float acc = lin_b[t];
        const float* lr = lin_w + t * LHID;
        for (int k = 0; k < LHID; ++k) acc += hh[k] * lr[k];
        out[g * COUT + t] = acc;
    }
}

extern "C" void kernel_launch(void* const* d_in, const int* in_sizes, int n_in,
                              void* d_out, int out_size, void* d_ws, size_t ws_size,
                              hipStream_t stream) {
    const float* x        = (const float*)d_in[0];
    const float* ncc      = (const float*)d_in[1];
    const int*   eidx     = (const int*)d_in[2];
    const int*   eattr    = (const int*)d_in[3];
    const int*   batch    = (const int*)d_in[4];
    const float* fc_w     = (const float*)d_in[5];
    const float* fc_b     = (const float*)d_in[6];
    const float* edge_emb = (const float*)d_in[7];
    const float* conv_w1  = (const float*)d_in[8];
    const float* conv_b1  = (const float*)d_in[9];
    const float* conv_bn_g= (const float*)d_in[10];
    const float* conv_bn_b= (const float*)d_in[11];
    const float* conv_w2  = (const float*)d_in[12];
    const float* conv_b2  = (const float*)d_in[13];
    const float* bn_g     = (const float*)d_in[14];
    const float* bn_b     = (const float*)d_in[15];
    const float* lstm_wih = (const float*)d_in[16];
    const float* lstm_bih = (const float*)d_in[18];
    const float* lstm_bhh = (const float*)d_in[19];
    const float* lin_w    = (const float*)d_in[20];
    const float* lin_b    = (const float*)d_in[21];
    float* out = (float*)d_out;

    const int* src = eidx;
    const int* dst = eidx + NEDGES;

    char* ws = (char*)d_ws;
    size_t o = 0;
    auto alloc = [&](size_t bytes) {
        size_t r = o;
        o += (bytes + 255) & ~(size_t)255;
        return r;
    };
    int*   deg    = (int*)(ws + alloc(NNODES * 4));
    int*   off    = (int*)(ws + alloc((NNODES + 1) * 4));
    int*   cursor = (int*)(ws + alloc(NNODES * 4));
    int*   pedge  = (int*)(ws + alloc(NEDGES * 4));
    int*   bsum   = (int*)(ws + alloc(256 * 4));
    int*   bpre   = (int*)(ws + alloc(256 * 4));
    float* h      = (float*)(ws + alloc((size_t)NNODES * HD * 4));
    float* x0     = (float*)(ws + alloc((size_t)NNODES * HD * 4));
    float* xmid   = (float*)(ws + alloc((size_t)NNODES * 2 * HD * 4));
    float* stats  = (float*)(ws + alloc(NLAYER * 768 * 4));
    float* p      = (float*)(ws + alloc((size_t)NGRAPH * HD * 4));

    // ---- CSR build ----
    hipMemsetAsync(deg, 0, NNODES * 4, stream);
    hipMemsetAsync(stats, 0, NLAYER * 768 * 4, stream);
    hist_kernel<<<(NEDGES + 255) / 256, 256, 0, stream>>>(dst, deg, NEDGES);
    blocksum_kernel<<<SCAN_BLOCKS, 256, 0, stream>>>(deg, bsum);
    scanpartials_kernel<<<1, 256, 0, stream>>>(bsum, bpre);
    writeoff_kernel<<<SCAN_BLOCKS, 256, 0, stream>>>(deg, bpre, off, cursor);
    scatter_kernel<<<(NEDGES + 255) / 256, 256, 0, stream>>>(src, dst, eattr, cursor, pedge, NEDGES);

    // ---- input FC ----
    fc_kernel<<<NNODES / 8, 256, 0, stream>>>(x, ncc, fc_w, fc_b, h);

    for (int l = 0; l < NLAYER; ++l) {
        float* sumsA = stats + l * 768;
        float* sqsA  = sumsA + 256;
        float* sumsB = sumsA + 512;
        float* sqsB  = sumsA + 640;
        if (l == 0)
            agg_kernel<false><<<NNODES / 4, 256, 0, stream>>>(
                h, off, pedge, edge_emb, nullptr, nullptr, nullptr, nullptr, x0);
        else {
            float* pB = stats + (l - 1) * 768;
            agg_kernel<true><<<NNODES / 4, 256, 0, stream>>>(
                h, off, pedge, edge_emb, pB + 512, pB + 640,
                bn_g + (l - 1) * HD, bn_b + (l - 1) * HD, x0);
        }
        {
            dim3 grid((NNODES + 127) / 128, 2);
            gemm_kernel<false><<<grid, 512, 0, stream>>>(
                x0, conv_w1 + (size_t)l * 2 * HD * HD, conv_b1 + l * 2 * HD,
                nullptr, nullptr, nullptr, nullptr,
                xmid, sumsA, sqsA, NNODES, 2 * HD, HD);
        }
        {
            dim3 grid((NNODES + 127) / 128, 1);
            gemm_kernel<true><<<grid, 512, 0, stream>>>(
                xmid, conv_w2 + (size_t)l * HD * 2 * HD, conv_b2 + l * HD,
                sumsA, sqsA, conv_bn_g + l * 2 * HD, conv_bn_b + l * 2 * HD,
                h, sumsB, sqsB, NNODES, HD, 2 * HD);
        }
    }

    {
        float* pB = stats + (NLAYER - 1) * 768;
        pool_kernel<<<NGRAPH, 256, 0, stream>>>(h, batch, pB + 512, pB + 640,
                                                bn_g + (NLAYER - 1) * HD,
                                                bn_b + (NLAYER - 1) * HD, p);
    }

    lstm_kernel<<<NGRAPH, 256, 0, stream>>>(p, lstm_wih, lstm_bih, lstm_bhh, lin_w, lin_b, out);
}

// Round 6
// 984.866 us; speedup vs baseline: 1.3588x; 1.3588x over previous
//
#include <hip/hip_runtime.h>
#include <hip/hip_bf16.h>
#include <math.h>

#define NNODES 50000
#define NEDGES 640000
#define NGRAPH 256
#define CIN 32
#define HD 128
#define NLAYER 5
#define LHID 64
#define COUT 10
#define EPS_GEN 1e-7f
#define INVN (1.f / (float)NNODES)
#define SCAN_BLOCKS 196

typedef __attribute__((ext_vector_type(8))) short short8;
typedef __attribute__((ext_vector_type(4))) float floatx4;

__device__ __forceinline__ unsigned short f2bf(float f) {
    union { float f; unsigned u; } v; v.f = f;
    unsigned r = v.u + 0x7FFFu + ((v.u >> 16) & 1u);
    return (unsigned short)(r >> 16);
}
__device__ __forceinline__ float bf2f(unsigned short h) {
    union { unsigned u; float f; } v; v.u = ((unsigned)h) << 16;
    return v.f;
}

// ---------------- CSR build ----------------
__global__ void hist_kernel(const int* __restrict__ dst, int* __restrict__ deg, int e) {
    int i = blockIdx.x * blockDim.x + threadIdx.x;
    if (i < e) atomicAdd(&deg[dst[i]], 1);
}

__global__ void blocksum_kernel(const int* __restrict__ deg, int* __restrict__ bsum) {
    int i = blockIdx.x * 256 + threadIdx.x;
    int v = (i < NNODES) ? deg[i] : 0;
#pragma unroll
    for (int d = 32; d; d >>= 1) v += __shfl_down(v, d);
    __shared__ int ws4[4];
    if ((threadIdx.x & 63) == 0) ws4[threadIdx.x >> 6] = v;
    __syncthreads();
    if (threadIdx.x == 0) bsum[blockIdx.x] = ws4[0] + ws4[1] + ws4[2] + ws4[3];
}

__global__ void scanpartials_kernel(const int* __restrict__ bsum, int* __restrict__ bpre) {
    __shared__ int t[256];
    int i = threadIdx.x;
    t[i] = (i < SCAN_BLOCKS) ? bsum[i] : 0;
    __syncthreads();
    for (int d = 1; d < 256; d <<= 1) {
        int v = (i >= d) ? t[i - d] : 0;
        __syncthreads();
        t[i] += v;
        __syncthreads();
    }
    bpre[i] = (i == 0) ? 0 : t[i - 1];
}

__global__ void writeoff_kernel(const int* __restrict__ deg, const int* __restrict__ bpre,
                                int* __restrict__ off, int* __restrict__ cursor) {
    __shared__ int t[256];
    int tid = threadIdx.x;
    int i = blockIdx.x * 256 + tid;
    int v = (i < NNODES) ? deg[i] : 0;
    t[tid] = v;
    __syncthreads();
    for (int d = 1; d < 256; d <<= 1) {
        int u = (tid >= d) ? t[tid - d] : 0;
        __syncthreads();
        t[tid] += u;
        __syncthreads();
    }
    int excl = bpre[blockIdx.x] + t[tid] - v;
    if (i < NNODES) { off[i] = excl; cursor[i] = excl; }
    if (i == NNODES - 1) off[NNODES] = excl + v;
}

__global__ void scatter_kernel(const int* __restrict__ src, const int* __restrict__ dst,
                               const int* __restrict__ eattr, int* __restrict__ cursor,
                               int* __restrict__ pedge, int e) {
    int i = blockIdx.x * blockDim.x + threadIdx.x;
    if (i < e) {
        int slot = atomicAdd(&cursor[dst[i]], 1);
        pedge[slot] = src[i] | (eattr[i] << 27);
    }
}

// ---------------- input FC ----------------
__global__ __launch_bounds__(256) void fc_kernel(
    const float* __restrict__ x, const float* __restrict__ ncc,
    const float* __restrict__ w, const float* __restrict__ b,
    float* __restrict__ h) {
    __shared__ float ws[HD][41];
    __shared__ float bs[HD];
    int tid = threadIdx.x;
    for (int i = tid; i < HD * 40; i += 256) ws[i / 40][i % 40] = w[i];
    if (tid < HD) bs[tid] = b[tid];
    __syncthreads();
    int c = tid & 127;
    int hi = tid >> 7;
#pragma unroll
    for (int nn = 0; nn < 4; ++nn) {
        int node = blockIdx.x * 8 + nn * 2 + hi;
        const float4* xr = reinterpret_cast<const float4*>(x + (size_t)node * CIN);
        const float4* nr = reinterpret_cast<const float4*>(ncc + (size_t)node * 8);
        float acc = bs[c];
#pragma unroll
        for (int k4 = 0; k4 < 8; ++k4) {
            float4 xv = xr[k4];
            acc += xv.x * ws[c][k4 * 4 + 0];
            acc += xv.y * ws[c][k4 * 4 + 1];
            acc += xv.z * ws[c][k4 * 4 + 2];
            acc += xv.w * ws[c][k4 * 4 + 3];
        }
#pragma unroll
        for (int k4 = 0; k4 < 2; ++k4) {
            float4 nv = nr[k4];
            acc += nv.x * ws[c][32 + k4 * 4 + 0];
            acc += nv.y * ws[c][32 + k4 * 4 + 1];
            acc += nv.z * ws[c][32 + k4 * 4 + 2];
            acc += nv.w * ws[c][32 + k4 * 4 + 3];
        }
        h[(size_t)node * HD + c] = acc;
    }
}

// ---------------- softmax aggregation ----------------
template <bool BN>
__global__ __launch_bounds__(256) void agg_kernel(
    const float* __restrict__ h, const int* __restrict__ off,
    const int* __restrict__ pedge, const float* __restrict__ edge_emb,
    const float* __restrict__ sums, const float* __restrict__ sqs,
    const float* __restrict__ g, const float* __restrict__ bb,
    float* __restrict__ x0) {
    __shared__ float ee[4 * HD];
    __shared__ float scs[HD], shs[HD];
    int tid = threadIdx.x;
    ee[tid] = edge_emb[tid];
    ee[tid + 256] = edge_emb[tid + 256];
    if (BN && tid < HD) {
        float mu = sums[tid] * INVN;
        float var = fmaxf(sqs[tid] * INVN - mu * mu, 0.f);
        float is = rsqrtf(var + 1e-5f);
        float sc = g[tid] * is;
        scs[tid] = sc;
        shs[tid] = bb[tid] - mu * sc;
    }
    __syncthreads();

    int node = blockIdx.x * 4 + (tid >> 6);
    int lane = tid & 63;
    int half = lane >> 5;
    int c4 = (lane & 31) * 4;

    int b = off[node], e = off[node + 1];
    float4 sc4 = make_float4(1.f, 1.f, 1.f, 1.f);
    float4 sh4 = make_float4(0.f, 0.f, 0.f, 0.f);
    if (BN) {
        sc4 = *reinterpret_cast<const float4*>(&scs[c4]);
        sh4 = *reinterpret_cast<const float4*>(&shs[c4]);
    }
    float4 S = make_float4(0.f, 0.f, 0.f, 0.f);
    float4 T = make_float4(0.f, 0.f, 0.f, 0.f);
    int j = b + half;
    unsigned pnext = (j < e) ? (unsigned)pedge[j] : 0u;
    for (; j < e; j += 2) {
        unsigned p = pnext;
        if (j + 2 < e) pnext = (unsigned)pedge[j + 2];
        int s = p & 0x07FFFFFFu;
        int a = p >> 27;
        float4 v = *reinterpret_cast<const float4*>(&h[(size_t)s * HD + c4]);
        float4 ev = *reinterpret_cast<const float4*>(&ee[a * HD + c4]);
        if (BN) {
            v.x = fmaxf(fmaf(v.x, sc4.x, sh4.x), 0.f);
            v.y = fmaxf(fmaf(v.y, sc4.y, sh4.y), 0.f);
            v.z = fmaxf(fmaf(v.z, sc4.z, sh4.z), 0.f);
            v.w = fmaxf(fmaf(v.w, sc4.w, sh4.w), 0.f);
        }
        float m0 = fmaxf(v.x + ev.x, 0.f) + EPS_GEN;
        float m1 = fmaxf(v.y + ev.y, 0.f) + EPS_GEN;
        float m2 = fmaxf(v.z + ev.z, 0.f) + EPS_GEN;
        float m3 = fmaxf(v.w + ev.w, 0.f) + EPS_GEN;
        float e0 = __expf(m0), e1 = __expf(m1), e2 = __expf(m2), e3 = __expf(m3);
        S.x += e0; S.y += e1; S.z += e2; S.w += e3;
        T.x = fmaf(e0, m0, T.x); T.y = fmaf(e1, m1, T.y);
        T.z = fmaf(e2, m2, T.z); T.w = fmaf(e3, m3, T.w);
    }
    S.x += __shfl(S.x, lane ^ 32); S.y += __shfl(S.y, lane ^ 32);
    S.z += __shfl(S.z, lane ^ 32); S.w += __shfl(S.w, lane ^ 32);
    T.x += __shfl(T.x, lane ^ 32); T.y += __shfl(T.y, lane ^ 32);
    T.z += __shfl(T.z, lane ^ 32); T.w += __shfl(T.w, lane ^ 32);
    if (half == 0) {
        float4 r = *reinterpret_cast<const float4*>(&h[(size_t)node * HD + c4]);
        if (BN) {
            r.x = fmaxf(fmaf(r.x, sc4.x, sh4.x), 0.f);
            r.y = fmaxf(fmaf(r.y, sc4.y, sh4.y), 0.f);
            r.z = fmaxf(fmaf(r.z, sc4.z, sh4.z), 0.f);
            r.w = fmaxf(fmaf(r.w, sc4.w, sh4.w), 0.f);
        }
        if (e > b) {
            r.x += T.x / S.x; r.y += T.y / S.y;
            r.z += T.z / S.z; r.w += T.w / S.w;
        }
        *reinterpret_cast<float4*>(&x0[(size_t)node * HD + c4]) = r;
    }
}

// ---------------- MFMA GEMM: split-bf16 (fp32-accurate) ----------------
// C[M,Nc] = op(A)[M,K] @ W[Nc,K]^T + bias, op = relu(a*scale+shift) if TRANS.
// A=Ah+Al, W=Wh+Wl in bf16; C = Ah*Wh + Al*Wh + Ah*Wl (Al*Wl ~2^-18, dropped).
// Tile: BM=128 x BN=64 x BK=32. 256 thr / 4 waves; wave -> 32 rows x 64 cols
// = 2x4 tiles of 16x16, v_mfma_f32_16x16x32_bf16.
// C/D layout (m89): col=lane&15, row=(lane>>4)*4+reg. A/B frag: [m|n=lane&15][k=(lane>>4)*8+j].
template <bool TRANS>
__global__ __launch_bounds__(256) void gemm_kernel(
    const float* __restrict__ A, const float* __restrict__ W,
    const float* __restrict__ bias,
    const float* __restrict__ sums_in, const float* __restrict__ sqs_in,
    const float* __restrict__ g_in, const float* __restrict__ b_in,
    float* __restrict__ C, float* __restrict__ sums, float* __restrict__ sqs,
    int M, int Nc, int K) {
    __shared__ short Ah[128][32];
    __shared__ short Al[128][32];
    __shared__ short Bh[64][32];
    __shared__ short Bl[64][32];
    __shared__ float scol[64], sqcol[64];
    __shared__ float sL[256], shL[256];
    int tid = threadIdx.x;
    if (tid < 64) { scol[tid] = 0.f; sqcol[tid] = 0.f; }
    if (TRANS && tid < K) {
        float mu = sums_in[tid] * INVN;
        float var = fmaxf(sqs_in[tid] * INVN - mu * mu, 0.f);
        float is = rsqrtf(var + 1e-5f);
        float sc = g_in[tid] * is;
        sL[tid] = sc;
        shL[tid] = b_in[tid] - mu * sc;
    }
    if (TRANS) __syncthreads();

    int m0 = blockIdx.x * 128;
    int n0 = blockIdx.y * 64;

    // staging coords
    int trow = tid >> 1;            // 0..127 (A row)
    int tcol = (tid & 1) * 16;      // 0/16
    int brow = tid >> 2;            // 0..63 (W row)
    int bcol = (tid & 3) * 8;       // 0,8,16,24
    int am = m0 + trow;
    bool mok = am < M;
    const float* aptr = A + (size_t)(mok ? am : 0) * K + tcol;
    const float* wptr = W + (size_t)(n0 + brow) * K + bcol;

    // compute coords
    int wv = tid >> 6;
    int lane = tid & 63;
    int ml = lane & 15;
    int quad = lane >> 4;

    floatx4 acc[2][4];
#pragma unroll
    for (int mt = 0; mt < 2; ++mt)
#pragma unroll
        for (int nt = 0; nt < 4; ++nt) acc[mt][nt] = (floatx4){0.f, 0.f, 0.f, 0.f};

    float4 ga[4], gb[2];
#pragma unroll
    for (int q = 0; q < 4; ++q) ga[q] = make_float4(0.f, 0.f, 0.f, 0.f);
    if (mok) {
#pragma unroll
        for (int q = 0; q < 4; ++q) ga[q] = *reinterpret_cast<const float4*>(aptr + q * 4);
    }
    gb[0] = *reinterpret_cast<const float4*>(wptr);
    gb[1] = *reinterpret_cast<const float4*>(wptr + 4);

    int niter = K >> 5;
    for (int it = 0; it < niter; ++it) {
        // convert + write LDS
        alignas(16) short avh[16], avl[16];
        alignas(16) short bvh[8], bvl[8];
        {
            int kbase = it * 32 + tcol;
#pragma unroll
            for (int q = 0; q < 4; ++q) {
                float vv[4] = {ga[q].x, ga[q].y, ga[q].z, ga[q].w};
#pragma unroll
                for (int e2 = 0; e2 < 4; ++e2) {
                    float v = vv[e2];
                    if (TRANS) {
                        int kg = kbase + q * 4 + e2;
                        v = fmaxf(fmaf(v, sL[kg], shL[kg]), 0.f);
                    }
                    unsigned short hb = f2bf(v);
                    avh[q * 4 + e2] = (short)hb;
                    avl[q * 4 + e2] = (short)f2bf(v - bf2f(hb));
                }
            }
            float wv2[8] = {gb[0].x, gb[0].y, gb[0].z, gb[0].w,
                            gb[1].x, gb[1].y, gb[1].z, gb[1].w};
#pragma unroll
            for (int e2 = 0; e2 < 8; ++e2) {
                unsigned short hb = f2bf(wv2[e2]);
                bvh[e2] = (short)hb;
                bvl[e2] = (short)f2bf(wv2[e2] - bf2f(hb));
            }
        }
        __syncthreads();   // previous iteration's compute done
        *reinterpret_cast<short8*>(&Ah[trow][tcol]) = *reinterpret_cast<short8*>(&avh[0]);
        *reinterpret_cast<short8*>(&Ah[trow][tcol + 8]) = *reinterpret_cast<short8*>(&avh[8]);
        *reinterpret_cast<short8*>(&Al[trow][tcol]) = *reinterpret_cast<short8*>(&avl[0]);
        *reinterpret_cast<short8*>(&Al[trow][tcol + 8]) = *reinterpret_cast<short8*>(&avl[8]);
        *reinterpret_cast<short8*>(&Bh[brow][bcol]) = *reinterpret_cast<short8*>(&bvh[0]);
        *reinterpret_cast<short8*>(&Bl[brow][bcol]) = *reinterpret_cast<short8*>(&bvl[0]);
        __syncthreads();
        // prefetch next K-tile while MFMAs run
        if (it + 1 < niter) {
            int koff = (it + 1) * 32;
            if (mok) {
#pragma unroll
                for (int q = 0; q < 4; ++q)
                    ga[q] = *reinterpret_cast<const float4*>(aptr + koff + q * 4);
            }
            gb[0] = *reinterpret_cast<const float4*>(wptr + koff);
            gb[1] = *reinterpret_cast<const float4*>(wptr + koff + 4);
        }
        // fragments
        short8 afh[2], afl[2], bfh[4], bfl[4];
#pragma unroll
        for (int mt = 0; mt < 2; ++mt) {
            int row = wv * 32 + mt * 16 + ml;
            afh[mt] = *reinterpret_cast<const short8*>(&Ah[row][quad * 8]);
            afl[mt] = *reinterpret_cast<const short8*>(&Al[row][quad * 8]);
        }
#pragma unroll
        for (int nt = 0; nt < 4; ++nt) {
            int row = nt * 16 + ml;
            bfh[nt] = *reinterpret_cast<const short8*>(&Bh[row][quad * 8]);
            bfl[nt] = *reinterpret_cast<const short8*>(&Bl[row][quad * 8]);
        }
#pragma unroll
        for (int mt = 0; mt < 2; ++mt)
#pragma unroll
            for (int nt = 0; nt < 4; ++nt) {
                acc[mt][nt] = __builtin_amdgcn_mfma_f32_16x16x32_bf16(afh[mt], bfh[nt], acc[mt][nt], 0, 0, 0);
                acc[mt][nt] = __builtin_amdgcn_mfma_f32_16x16x32_bf16(afl[mt], bfh[nt], acc[mt][nt], 0, 0, 0);
                acc[mt][nt] = __builtin_amdgcn_mfma_f32_16x16x32_bf16(afh[mt], bfl[nt], acc[mt][nt], 0, 0, 0);
            }
    }

    // epilogue: bias + store + column stats
#pragma unroll
    for (int nt = 0; nt < 4; ++nt) {
        int colL = nt * 16 + ml;
        int col = n0 + colL;
        float bv = bias[col];
        float cs = 0.f, cq = 0.f;
#pragma unroll
        for (int mt = 0; mt < 2; ++mt) {
#pragma unroll
            for (int r = 0; r < 4; ++r) {
                int m = m0 + wv * 32 + mt * 16 + quad * 4 + r;
                if (m < M) {
                    float v = acc[mt][nt][r] + bv;
                    C[(size_t)m * Nc + col] = v;
                    cs += v; cq += v * v;
                }
            }
        }
        atomicAdd(&scol[colL], cs);
        atomicAdd(&sqcol[colL], cq);
    }
    __syncthreads();
    if (tid < 64) {
        atomicAdd(&sums[n0 + tid], scol[tid]);
        atomicAdd(&sqs[n0 + tid], sqcol[tid]);
    }
}

// ---------------- segmented pool + folded final BN+ReLU ----------------
__global__ void pool_kernel(const float* __restrict__ h, const int* __restrict__ batch,
                            const float* __restrict__ sums, const float* __restrict__ sqs,
                            const float* __restrict__ g, const float* __restrict__ bb,
                            float* __restrict__ p) {
    __shared__ int range[2];
    __shared__ float acc2[256];
    int gid = blockIdx.x;
    int tid = threadIdx.x;
    if (tid < 2) {
        int target = gid + tid;
        int lo = 0, hi = NNODES;
        while (lo < hi) {
            int mid = (lo + hi) >> 1;
            if (batch[mid] < target) lo = mid + 1; else hi = mid;
        }
        range[tid] = lo;
    }
    __syncthreads();
    int s0 = range[0], s1 = range[1];
    int c = tid & 127;
    int half = tid >> 7;
    float mu = sums[c] * INVN;
    float var = fmaxf(sqs[c] * INVN - mu * mu, 0.f);
    float is = rsqrtf(var + 1e-5f);
    float sc = g[c] * is;
    float sh = bb[c] - mu * sc;
    float a = 0.f;
    for (int r = s0 + half; r < s1; r += 2)
        a += fmaxf(fmaf(h[(size_t)r * HD + c], sc, sh), 0.f);
    acc2[tid] = a;
    __syncthreads();
    if (half == 0) p[gid * HD + c] = acc2[c] + acc2[c + 128];
}

// ---------------- LSTM (1 step) + final linear ----------------
__global__ void lstm_kernel(const float* __restrict__ p, const float* __restrict__ wih,
                            const float* __restrict__ bih, const float* __restrict__ bhh,
                            const float* __restrict__ lin_w, const float* __restrict__ lin_b,
                            float* __restrict__ out) {
    __shared__ float pr[HD];
    __shared__ float gates[4 * LHID];
    __shared__ float hh[LHID];
    int g = blockIdx.x;
    int t = threadIdx.x;
    if (t < HD) pr[t] = p[g * HD + t];
    __syncthreads();
    {
        float acc = bih[t] + bhh[t];
        const float* wr = wih + t * HD;
        for (int k = 0; k < HD; ++k) acc += pr[k] * wr[k];
        gates[t] = acc;
    }
    __syncthreads();
    if (t < LHID) {
        float ig = gates[t];
        float gg = gates[2 * LHID + t];
        float og = gates[3 * LHID + t];
        float c = (1.f / (1.f + __expf(-ig))) * tanhf(gg);
        hh[t] = (1.f / (1.f + __expf(-og))) * tanhf(c);
    }
    __syncthreads();
    if (t < COUT) {
        float acc = lin_b[t];
        const float* lr = lin_w + t * LHID;
        for (int k = 0; k < LHID; ++k) acc += hh[k] * lr[k];
        out[g * COUT + t] = acc;
    }
}

extern "C" void kernel_launch(void* const* d_in, const int* in_sizes, int n_in,
                              void* d_out, int out_size, void* d_ws, size_t ws_size,
                              hipStream_t stream) {
    const float* x        = (const float*)d_in[0];
    const float* ncc      = (const float*)d_in[1];
    const int*   eidx     = (const int*)d_in[2];
    const int*   eattr    = (const int*)d_in[3];
    const int*   batch    = (const int*)d_in[4];
    const float* fc_w     = (const float*)d_in[5];
    const float* fc_b     = (const float*)d_in[6];
    const float* edge_emb = (const float*)d_in[7];
    const float* conv_w1  = (const float*)d_in[8];
    const float* conv_b1  = (const float*)d_in[9];
    const float* conv_bn_g= (const float*)d_in[10];
    const float* conv_bn_b= (const float*)d_in[11];
    const float* conv_w2  = (const float*)d_in[12];
    const float* conv_b2  = (const float*)d_in[13];
    const float* bn_g     = (const float*)d_in[14];
    const float* bn_b     = (const float*)d_in[15];
    const float* lstm_wih = (const float*)d_in[16];
    const float* lstm_bih = (const float*)d_in[18];
    const float* lstm_bhh = (const float*)d_in[19];
    const float* lin_w    = (const float*)d_in[20];
    const float* lin_b    = (const float*)d_in[21];
    float* out = (float*)d_out;

    const int* src = eidx;
    const int* dst = eidx + NEDGES;

    char* ws = (char*)d_ws;
    size_t o = 0;
    auto alloc = [&](size_t bytes) {
        size_t r = o;
        o += (bytes + 255) & ~(size_t)255;
        return r;
    };
    int*   deg    = (int*)(ws + alloc(NNODES * 4));
    int*   off    = (int*)(ws + alloc((NNODES + 1) * 4));
    int*   cursor = (int*)(ws + alloc(NNODES * 4));
    int*   pedge  = (int*)(ws + alloc(NEDGES * 4));
    int*   bsum   = (int*)(ws + alloc(256 * 4));
    int*   bpre   = (int*)(ws + alloc(256 * 4));
    float* h      = (float*)(ws + alloc((size_t)NNODES * HD * 4));
    float* x0     = (float*)(ws + alloc((size_t)NNODES * HD * 4));
    float* xmid   = (float*)(ws + alloc((size_t)NNODES * 2 * HD * 4));
    float* stats  = (float*)(ws + alloc(NLAYER * 768 * 4));
    float* p      = (float*)(ws + alloc((size_t)NGRAPH * HD * 4));

    // ---- CSR build ----
    hipMemsetAsync(deg, 0, NNODES * 4, stream);
    hipMemsetAsync(stats, 0, NLAYER * 768 * 4, stream);
    hist_kernel<<<(NEDGES + 255) / 256, 256, 0, stream>>>(dst, deg, NEDGES);
    blocksum_kernel<<<SCAN_BLOCKS, 256, 0, stream>>>(deg, bsum);
    scanpartials_kernel<<<1, 256, 0, stream>>>(bsum, bpre);
    writeoff_kernel<<<SCAN_BLOCKS, 256, 0, stream>>>(deg, bpre, off, cursor);
    scatter_kernel<<<(NEDGES + 255) / 256, 256, 0, stream>>>(src, dst, eattr, cursor, pedge, NEDGES);

    // ---- input FC ----
    fc_kernel<<<NNODES / 8, 256, 0, stream>>>(x, ncc, fc_w, fc_b, h);

    for (int l = 0; l < NLAYER; ++l) {
        float* sumsA = stats + l * 768;
        float* sqsA  = sumsA + 256;
        float* sumsB = sumsA + 512;
        float* sqsB  = sumsA + 640;
        if (l == 0)
            agg_kernel<false><<<NNODES / 4, 256, 0, stream>>>(
                h, off, pedge, edge_emb, nullptr, nullptr, nullptr, nullptr, x0);
        else {
            float* pB = stats + (l - 1) * 768;
            agg_kernel<true><<<NNODES / 4, 256, 0, stream>>>(
                h, off, pedge, edge_emb, pB + 512, pB + 640,
                bn_g + (l - 1) * HD, bn_b + (l - 1) * HD, x0);
        }
        {
            dim3 grid((NNODES + 127) / 128, 4);   // N=256 in 64-col panels
            gemm_kernel<false><<<grid, 256, 0, stream>>>(
                x0, conv_w1 + (size_t)l * 2 * HD * HD, conv_b1 + l * 2 * HD,
                nullptr, nullptr, nullptr, nullptr,
                xmid, sumsA, sqsA, NNODES, 2 * HD, HD);
        }
        {
            dim3 grid((NNODES + 127) / 128, 2);   // N=128 in 64-col panels
            gemm_kernel<true><<<grid, 256, 0, stream>>>(
                xmid, conv_w2 + (size_t)l * HD * 2 * HD, conv_b2 + l * HD,
                sumsA, sqsA, conv_bn_g + l * 2 * HD, conv_bn_b + l * 2 * HD,
                h, sumsB, sqsB, NNODES, HD, 2 * HD);
        }
    }

    {
        float* pB = stats + (NLAYER - 1) * 768;
        pool_kernel<<<NGRAPH, 256, 0, stream>>>(h, batch, pB + 512, pB + 640,
                                                bn_g + (NLAYER - 1) * HD,
                                                bn_b + (NLAYER - 1) * HD, p);
    }

    lstm_kernel<<<NGRAPH, 256, 0, stream>>>(p, lstm_wih, lstm_bih, lstm_bhh, lin_w, lin_b, out);
}